// Round 12
// baseline (3106.836 us; speedup 1.0000x reference)
//
#include <hip/hip_runtime.h>

// Causal linear attention (ELU+1), chunked prefix-scan — SINGLE fused kernel
// with per-wave chained decoupled scan (no grid.sync, no separate scan pass).
// Shapes: q,k,v,out = [B=2, T=2048, H=16, D=64] fp32, layout [B,T,H,D].
//
// R10 lesson: 3-kernel pipeline floor = fill(42us) + 3x(staging+launch+tail).
// R5 lesson: grid.sync costs ~200us+/barrier -> forbidden. Instead: block
// (bh,c) waits only on (bh,c-1) via agent-scope flags; 32-hop wave chains,
// XCD-local by construction (bid%8 invariant in c). 4 blocks/CU -> all 1024
// co-resident; deadlock-free under in-order dispatch (pred has lower bid)
// at ANY occupancy. Spin guard (1<<24) fails loud, never hangs.
//
// Fragment conventions (gfx950 16x16x32 bf16), verified R8-R10:
//   A-frag: lane = m + 16*kblk holds A[m][kblk*8+i]   (read ROW m of tile)
//   B-frag: lane = n + 16*kblk holds B[kblk*8+i][n]   (read ROW n of B^T tile)
//   C/D:    lane holds D[(lane>>4)*4+j][lane&15]

#define BQ 2
#define TT 2048
#define HH 16
#define DD 64
#define CC 64
#define NC (TT / CC)      // 32 chunks per (b,h)
#define BH (BQ * HH)      // 32
#define NCH (BH * NC)     // 1024 blocks
#define LDU 72            // ushort LDS stride: 144B rows

typedef __attribute__((ext_vector_type(8))) short short8;
typedef __attribute__((ext_vector_type(4))) float f32x4;

__device__ __forceinline__ float phi_f(float x) {
    return x > 0.f ? x + 1.f : __expf(x);   // elu(x)+1
}
__device__ __forceinline__ unsigned short f2bf(float f) {   // fp32 -> bf16 RNE
    unsigned int u = __float_as_uint(f);
    u += 0x7FFFu + ((u >> 16) & 1u);
    return (unsigned short)(u >> 16);
}
__device__ __forceinline__ float bf2f(unsigned short s) {
    return __uint_as_float(((unsigned int)s) << 16);
}

__global__ __launch_bounds__(256, 4) void k_fused(const float* __restrict__ Q,
                                                  const float* __restrict__ K,
                                                  const float* __restrict__ V,
                                                  int* __restrict__ flags,
                                                  float* __restrict__ wsZ,
                                                  float* __restrict__ wsS,
                                                  float* __restrict__ O) {
    __shared__ __align__(16) unsigned short Kt[DD][LDU];  // phiK^T; later S_prev^T (bf16)
    __shared__ __align__(16) unsigned short Vt[DD][LDU];  // V^T (state A + PV B)
    __shared__ __align__(16) unsigned short Kb[CC][LDU];  // phiK rows; later masked scores
    __shared__ __align__(16) unsigned short Qb[CC][LDU];  // phiQ rows
    __shared__ float zp[DD];                              // z_prev (exclusive)

    const int bid = blockIdx.x;
    const int bh = bid & 31, c = bid >> 5;   // chunks of a bh share XCD (bid%8 fixed)
    const int b = bh / HH, h = bh % HH;
    const int t0 = c * CC;
    const int cid = bh * NC + c;             // ws index; predecessor = cid-1
    const int tid = threadIdx.x;

    // ---------- stage: K,V,Q -> LDS (phi + bf16) ----------
#pragma unroll
    for (int w = 0; w < 4; ++w) {
        const int idx = tid + (w << 8);
        const int r = idx >> 4, q4 = (idx & 15) << 2;   // r = t-row, q4 = d-quad
        const int g = (((b * TT + t0 + r) * HH + h) << 6) + q4;
        const float4 kv = *(const float4*)(K + g);
        ushort4 pk;
        pk.x = f2bf(phi_f(kv.x)); pk.y = f2bf(phi_f(kv.y));
        pk.z = f2bf(phi_f(kv.z)); pk.w = f2bf(phi_f(kv.w));
        Kt[q4 + 0][r] = pk.x; Kt[q4 + 1][r] = pk.y;
        Kt[q4 + 2][r] = pk.z; Kt[q4 + 3][r] = pk.w;
        *(ushort4*)&Kb[r][q4] = pk;
        const float4 vv = *(const float4*)(V + g);
        Vt[q4 + 0][r] = f2bf(vv.x);
        Vt[q4 + 1][r] = f2bf(vv.y);
        Vt[q4 + 2][r] = f2bf(vv.z);
        Vt[q4 + 3][r] = f2bf(vv.w);
        const float4 qv = *(const float4*)(Q + g);
        ushort4 pq;
        pq.x = f2bf(phi_f(qv.x)); pq.y = f2bf(phi_f(qv.y));
        pq.z = f2bf(phi_f(qv.z)); pq.w = f2bf(phi_f(qv.w));
        *(ushort4*)&Qb[r][q4] = pq;
    }
    __syncthreads();   // (1) stage complete

    const int wid = tid >> 6, lane = tid & 63;
    const int rg = lane >> 4, cl = lane & 15;
    f32x4 zero4 = {0.f, 0.f, 0.f, 0.f};

    // ---------- per-chunk delta: dS^T[e][d], wave wid owns e-band 16*wid..+15
    f32x4 acc[4] = {zero4, zero4, zero4, zero4};
#pragma unroll
    for (int kk = 0; kk < 2; ++kk) {
        const short8 a = *(const short8*)&Vt[16 * wid + cl][kk * 32 + rg * 8];
#pragma unroll
        for (int nt = 0; nt < 4; ++nt) {
            const short8 bb = *(const short8*)&Kt[16 * nt + cl][kk * 32 + rg * 8];
            acc[nt] = __builtin_amdgcn_mfma_f32_16x16x32_bf16(a, bb, acc[nt], 0, 0, 0);
        }
    }
    // z own-sum (wave 0: lane = d)
    float zown = 0.f;
    if (tid < DD) {
#pragma unroll
        for (int tb = 0; tb < 8; ++tb) {
            const short8 v = *(const short8*)&Kt[tid][tb * 8];
#pragma unroll
            for (int i = 0; i < 8; ++i) zown += bf2f((unsigned short)v[i]);
        }
    }
    __syncthreads();   // (2) all Kt reads done (Kt will hold S_prev^T next)

    // ---------- chained scan: wave-level spin on (bh,c-1)'s matching band ----
    float sp[4][4];
    if (c > 0) {
        const int pflag = (cid - 1) * 4 + wid;
        int guard = 0;
        while (__hip_atomic_load(&flags[pflag], __ATOMIC_ACQUIRE,
                                 __HIP_MEMORY_SCOPE_AGENT) == 0) {
            __builtin_amdgcn_s_sleep(2);
            if (++guard > (1 << 24)) break;   // bounded: fail loud, not hung
        }
        const float* P = wsS + (size_t)(cid - 1) * (DD * DD);
#pragma unroll
        for (int nt = 0; nt < 4; ++nt)
#pragma unroll
            for (int j = 0; j < 4; ++j)
                sp[nt][j] = P[(16 * wid + 4 * rg + j) * DD + 16 * nt + cl];
        if (tid < DD) {
            const float zprev = wsZ[(size_t)(cid - 1) * DD + tid];
            zp[tid] = zprev;
            if (c < NC - 1) wsZ[(size_t)cid * DD + tid] = zprev + zown;
        }
    } else {
#pragma unroll
        for (int nt = 0; nt < 4; ++nt)
#pragma unroll
            for (int j = 0; j < 4; ++j) sp[nt][j] = 0.f;
        if (tid < DD) {
            zp[tid] = 0.f;
            wsZ[(size_t)cid * DD + tid] = zown;
        }
    }
    // S_prev^T (exclusive, bf16) into Kt; inclusive fp32 -> ws; release flag.
    // Last chunk (c == NC-1) has no consumer: skip publish.
    {
        float* Pw = wsS + (size_t)cid * (DD * DD);
        const bool pub = (c < NC - 1);
#pragma unroll
        for (int nt = 0; nt < 4; ++nt)
#pragma unroll
            for (int j = 0; j < 4; ++j) {
                Kt[16 * wid + 4 * rg + j][16 * nt + cl] = f2bf(sp[nt][j]);
                if (pub)
                    Pw[(16 * wid + 4 * rg + j) * DD + 16 * nt + cl] =
                        sp[nt][j] + acc[nt][j];
            }
        if (pub) {
            __threadfence();
            if (lane == 0)
                __hip_atomic_store(&flags[cid * 4 + wid], 1, __ATOMIC_RELEASE,
                                   __HIP_MEMORY_SCOPE_AGENT);
        }
    }
    __syncthreads();   // (3) S_prev^T + zp visible block-wide

    // ---------- scores: D[q][kv] (Qb x Kb), only nt <= wid (causal bands) ----
    f32x4 sc[4] = {zero4, zero4, zero4, zero4};
#pragma unroll
    for (int kk = 0; kk < 2; ++kk) {
        const short8 a = *(const short8*)&Qb[16 * wid + cl][kk * 32 + rg * 8];
        for (int nt = 0; nt <= wid; ++nt) {
            const short8 bb = *(const short8*)&Kb[16 * nt + cl][kk * 32 + rg * 8];
            sc[nt] = __builtin_amdgcn_mfma_f32_16x16x32_bf16(a, bb, sc[nt], 0, 0, 0);
        }
    }

    // ---------- causal mask + den4; dint = phiQ . z_prev ----------
    float den4[4], dint[4];
    const float4 zq = *(const float4*)&zp[4 * cl];
#pragma unroll
    for (int j = 0; j < 4; ++j) {
        const int qrow = 16 * wid + 4 * rg + j;
        float s = 0.f;
        for (int nt = 0; nt <= wid; ++nt) {
            if (16 * nt + cl > qrow) sc[nt][j] = 0.f;
            s += sc[nt][j];
        }
        den4[j] = s;
        const ushort4 qv = *(const ushort4*)&Qb[qrow][4 * cl];
        dint[j] = bf2f(qv.x) * zq.x + bf2f(qv.y) * zq.y +
                  bf2f(qv.z) * zq.z + bf2f(qv.w) * zq.w;
    }
#pragma unroll
    for (int m = 1; m < 16; m <<= 1)
#pragma unroll
        for (int j = 0; j < 4; ++j) {
            den4[j] += __shfl_xor(den4[j], m, 64);
            dint[j] += __shfl_xor(dint[j], m, 64);
        }

    // ---------- inter-chunk: o = phiQ @ S_prev (B = S_prev^T rows in Kt) ----
    f32x4 oa[4] = {zero4, zero4, zero4, zero4};
#pragma unroll
    for (int kk = 0; kk < 2; ++kk) {
        const short8 a = *(const short8*)&Qb[16 * wid + cl][kk * 32 + rg * 8];
#pragma unroll
        for (int nt = 0; nt < 4; ++nt) {
            const short8 bb = *(const short8*)&Kt[16 * nt + cl][kk * 32 + rg * 8];
            oa[nt] = __builtin_amdgcn_mfma_f32_16x16x32_bf16(a, bb, oa[nt], 0, 0, 0);
        }
    }

    __syncthreads();   // (4) everyone done reading Kb (scores inputs)
#pragma unroll
    for (int nt = 0; nt < 4; ++nt)
#pragma unroll
        for (int j = 0; j < 4; ++j)
            Kb[16 * wid + 4 * rg + j][16 * nt + cl] =
                (nt <= wid) ? f2bf(sc[nt][j]) : (unsigned short)0;
    __syncthreads();   // (5) masked scores staged

    // ---------- PV: o += A @ V (A = masked scores, B = V^T rows) ----------
    const int kkmax = (wid >= 2) ? 2 : 1;
    for (int kk = 0; kk < kkmax; ++kk) {
        const short8 a = *(const short8*)&Kb[16 * wid + cl][kk * 32 + rg * 8];
#pragma unroll
        for (int nt = 0; nt < 4; ++nt) {
            const short8 bb = *(const short8*)&Vt[16 * nt + cl][kk * 32 + rg * 8];
            oa[nt] = __builtin_amdgcn_mfma_f32_16x16x32_bf16(a, bb, oa[nt], 0, 0, 0);
        }
    }

    // ---------- epilogue ----------
#pragma unroll
    for (int j = 0; j < 4; ++j) {
        const int qrow = 16 * wid + 4 * rg + j;
        const float inv = 1.0f / (den4[j] + dint[j] + 1e-6f);
        const int gbase = (((b * TT + t0 + qrow) * HH + h) << 6);
#pragma unroll
        for (int nt = 0; nt < 4; ++nt)
            O[gbase + 16 * nt + cl] = oa[nt][j] * inv;
    }
}

extern "C" void kernel_launch(void* const* d_in, const int* in_sizes, int n_in,
                              void* d_out, int out_size, void* d_ws, size_t ws_size,
                              hipStream_t stream) {
    const float* q = (const float*)d_in[0];
    const float* k = (const float*)d_in[1];
    const float* v = (const float*)d_in[2];
    float* out = (float*)d_out;

    int* flags = (int*)d_ws;                                   // 1024*4 ints (16 KB)
    float* wsZ = (float*)(flags + NCH * 4);                    // 1024*64 fp32 (256 KB)
    float* wsS = wsZ + (size_t)NCH * DD;                       // 1024*4096 fp32 (16.8 MB)

    hipMemsetAsync(flags, 0, NCH * 4 * sizeof(int), stream);
    k_fused<<<NCH, 256, 0, stream>>>(q, k, v, flags, wsZ, wsS, out);
}